// Round 20
// baseline (1062.274 us; speedup 1.0000x reference)
//
#include <hip/hip_runtime.h>
#include <math.h>

#define NDIM 64
#define KSTEPS 32
typedef float f32x2 __attribute__((ext_vector_type(2)));

#define MEMFENCE() asm volatile("" ::: "memory")

// Broadcast lane `lane`'s value to all lanes (uniform / SGPR).
__device__ __forceinline__ float rl(float v, int lane) {
    return __uint_as_float((unsigned)__builtin_amdgcn_readlane(__float_as_uint(v), lane));
}

// DPP add step with compile-time control/row mask.
template<int CTRL, int ROW_MASK>
__device__ __forceinline__ float dpp_add(float x) {
    int m = __builtin_amdgcn_update_dpp(0, __float_as_int(x), CTRL, ROW_MASK, 0xf, true);
    return x + __int_as_float(m);
}
// Full-wave64 sum via DPP; total lands in lane 63, broadcast via readlane.
__device__ __forceinline__ float wave_sum(float x) {
    x = dpp_add<0x111, 0xf>(x);   // row_shr:1
    x = dpp_add<0x112, 0xf>(x);   // row_shr:2
    x = dpp_add<0x114, 0xf>(x);   // row_shr:4
    x = dpp_add<0x118, 0xf>(x);   // row_shr:8
    x = dpp_add<0x142, 0xa>(x);   // row_bcast:15 -> rows 1,3
    x = dpp_add<0x143, 0xc>(x);   // row_bcast:31 -> row 3
    return rl(x, 63);
}
__device__ __forceinline__ float wave_min(float v) {
    #pragma unroll
    for (int off = 1; off < 64; off <<= 1) v = fminf(v, __shfl_xor(v, off, 64));
    return v;
}
__device__ __forceinline__ float wave_max(float v) {
    #pragma unroll
    for (int off = 1; off < 64; off <<= 1) v = fmaxf(v, __shfl_xor(v, off, 64));
    return v;
}

// Build symmetrized row t into r2 (32 x f32x2) using readlane broadcasts
// (used by the householder fallback path only).
__device__ __forceinline__ void build_rows(f32x2 (&r2)[32], const float* ws,
                                           float xi, float yi, int t) {
    const float4* Sa4 = (const float4*)(ws + t * NDIM);
    const float4* Bh4 = (const float4*)(ws + 4096 + t * NDIM);
    const float4* Bt4 = (const float4*)(ws + 8192 + t * NDIM);
    const float4* Ch4 = (const float4*)(ws + 12288 + t * NDIM);
    const float4* Ct4 = (const float4*)(ws + 16384 + t * NDIM);
    #pragma unroll
    for (int q = 0; q < 16; ++q) {
        float4 sa = Sa4[q], bh = Bh4[q], bt = Bt4[q], ch = Ch4[q], ct = Ct4[q];
        float x0 = rl(xi, 4 * q),     y0 = rl(yi, 4 * q);
        float x1 = rl(xi, 4 * q + 1), y1 = rl(yi, 4 * q + 1);
        float x2 = rl(xi, 4 * q + 2), y2 = rl(yi, 4 * q + 2);
        float x3 = rl(xi, 4 * q + 3), y3 = rl(yi, 4 * q + 3);
        float e0 = fmaf(bh.x, x0, fmaf(bt.x, xi, fmaf(ch.x, y0, fmaf(ct.x, yi, sa.x))));
        float e1 = fmaf(bh.y, x1, fmaf(bt.y, xi, fmaf(ch.y, y1, fmaf(ct.y, yi, sa.y))));
        float e2 = fmaf(bh.z, x2, fmaf(bt.z, xi, fmaf(ch.z, y2, fmaf(ct.z, yi, sa.z))));
        float e3 = fmaf(bh.w, x3, fmaf(bt.w, xi, fmaf(ch.w, y3, fmaf(ct.w, yi, sa.w))));
        r2[2 * q].x = e0;     r2[2 * q].y = e1;
        r2[2 * q + 1].x = e2; r2[2 * q + 1].y = e3;
    }
}

// Shared tail: Gershgorin bounds over lanes < NACT + 64-way Sturm multisection
// (register/readlane form; recurrence length NACT at compile time).
template<int NACT>
__device__ __forceinline__ void sturm_out(float dval, float e2val, int idx,
                                          int t, int b, float* out) {
    bool act = (t < NACT);
    float eabs = sqrtf(e2val);
    float eprev = __shfl_up(eabs, 1, 64);
    eprev = (t == 0) ? 0.0f : eprev;
    float rad = eabs + eprev;
    float lo = wave_min(act ? dval - rad : 1e30f);
    float hi = wave_max(act ? dval + rad : -1e30f);
    float pad = 1e-3f + 1e-5f * fmaxf(fabsf(lo), fabsf(hi));
    lo -= pad;
    hi += pad;

    #pragma unroll 1
    for (int it = 0; it < 2; ++it) {
        float wdt = (hi - lo) * (1.0f / 65.0f);
        float s = lo + wdt * (float)(t + 1);
        float q = rl(dval, 0) - s;
        q = (fabsf(q) < 1e-12f) ? -1e-12f : q;
        int cnt = (q < 0.0f) ? 1 : 0;
        #pragma unroll
        for (int i = 1; i < NACT; ++i) {
            q = rl(dval, i) - s - rl(e2val, i - 1) * __builtin_amdgcn_rcpf(q);
            q = (fabsf(q) < 1e-12f) ? -1e-12f : q;
            cnt += (q < 0.0f) ? 1 : 0;
        }
        unsigned long long m = __ballot(cnt <= idx);
        int p = (int)__popcll(m);
        float nlo = lo + wdt * (float)p;
        float nhi = lo + wdt * (float)(p + 1);
        lo = nlo;
        hi = (p >= 64) ? hi : nhi;
    }
    if (t == 0) out[b] = 0.5f * (lo + hi);
}

// One-time prep: Sa = 0.5(A+A^T), Bh = 0.5B, Bt = 0.5B^T, Ch = 0.5C, Ct = 0.5C^T.
__global__ __launch_bounds__(64)
void prep_kernel(const float* __restrict__ A, const float* __restrict__ B,
                 const float* __restrict__ C, float* __restrict__ ws) {
    const int t = threadIdx.x;
    float* Sa = ws;
    float* Bh = ws + 4096;
    float* Bt = ws + 8192;
    float* Ch = ws + 12288;
    float* Ct = ws + 16384;
    for (int j = 0; j < NDIM; ++j) {
        Sa[t * NDIM + j] = 0.5f * (A[t * NDIM + j] + A[j * NDIM + t]);
        Bh[t * NDIM + j] = 0.5f * B[t * NDIM + j];
        Bt[t * NDIM + j] = 0.5f * B[j * NDIM + t];
        Ch[t * NDIM + j] = 0.5f * C[t * NDIM + j];
        Ct[t * NDIM + j] = 0.5f * C[j * NDIM + t];
    }
}

// ===== Truncated Lanczos (K=32), extreme indices (idx==0 or idx==63).
// Build fully in pk-FMA (x/y via LDS f32x2 broadcast). q-buffer typed f32x2
// feeds v_pk_fma directly. launch_bounds(256,8): VGPR<=64 -> 8 waves/SIMD.
__global__ __launch_bounds__(256, 8)
void lanczos_kernel(const float* __restrict__ x, const float* __restrict__ y,
                    const float* __restrict__ ws, const int* __restrict__ idxp,
                    float* __restrict__ out, int batch) {
    int idx = idxp[0];
    idx = idx < 0 ? 0 : (idx > NDIM - 1 ? NDIM - 1 : idx);
    if (idx != 0 && idx != NDIM - 1) return;   // interior: householder kernel
    const int idx_eff = (idx == 0) ? 0 : (KSTEPS - 1);

    const int t = threadIdx.x & 63;
    const int wv = threadIdx.x >> 6;
    const int b = blockIdx.x * 4 + wv;
    if (b >= batch) return;

    __shared__ f32x2 qbs[4][64];
    __shared__ float ybs[4][64];
    f32x2* qb2 = qbs[wv];
    float* qbp = (float*)qb2;
    float* ybp = ybs[wv];

    const float xi = x[b * NDIM + t];
    const float yi = y[b * NDIM + t];
    qbp[t] = xi;                       // x broadcast (buffer reused for q later)
    ybp[t] = yi;                       // y broadcast
    MEMFENCE();

    const float4* Sa4 = (const float4*)(ws + t * NDIM);
    const float4* Bh4 = (const float4*)(ws + 4096 + t * NDIM);
    const float4* Bt4 = (const float4*)(ws + 8192 + t * NDIM);
    const float4* Ch4 = (const float4*)(ws + 12288 + t * NDIM);
    const float4* Ct4 = (const float4*)(ws + 16384 + t * NDIM);
    const f32x2* xb2 = (const f32x2*)qbp;
    const f32x2* yb2 = (const f32x2*)ybp;

    f32x2 xi2; xi2.x = xi; xi2.y = xi;
    f32x2 yi2; yi2.x = yi; yi2.y = yi;

    // r_sym[t] = Sa + Bh*x[j] + Bt*x[t] + Ch*y[j] + Ct*y[t], all pk-FMA.
    f32x2 r2[32];
    #pragma unroll
    for (int qd = 0; qd < 16; ++qd) {
        float4 sa = Sa4[qd], bh = Bh4[qd], bt = Bt4[qd], ch = Ch4[qd], ct = Ct4[qd];
        f32x2 sa01; sa01.x = sa.x; sa01.y = sa.y;
        f32x2 sa23; sa23.x = sa.z; sa23.y = sa.w;
        f32x2 bh01; bh01.x = bh.x; bh01.y = bh.y;
        f32x2 bh23; bh23.x = bh.z; bh23.y = bh.w;
        f32x2 bt01; bt01.x = bt.x; bt01.y = bt.y;
        f32x2 bt23; bt23.x = bt.z; bt23.y = bt.w;
        f32x2 ch01; ch01.x = ch.x; ch01.y = ch.y;
        f32x2 ch23; ch23.x = ch.z; ch23.y = ch.w;
        f32x2 ct01; ct01.x = ct.x; ct01.y = ct.y;
        f32x2 ct23; ct23.x = ct.z; ct23.y = ct.w;
        f32x2 x01 = xb2[2 * qd], x23 = xb2[2 * qd + 1];
        f32x2 y01 = yb2[2 * qd], y23 = yb2[2 * qd + 1];
        f32x2 r01 = __builtin_elementwise_fma(bh01, x01,
                    __builtin_elementwise_fma(bt01, xi2,
                    __builtin_elementwise_fma(ch01, y01,
                    __builtin_elementwise_fma(ct01, yi2, sa01))));
        f32x2 r23 = __builtin_elementwise_fma(bh23, x23,
                    __builtin_elementwise_fma(bt23, xi2,
                    __builtin_elementwise_fma(ch23, y23,
                    __builtin_elementwise_fma(ct23, yi2, sa23))));
        r2[2 * qd] = r01;
        r2[2 * qd + 1] = r23;
    }
    MEMFENCE();                        // all xb2 reads issued before q0 overwrite

    // Lanczos: q0 = e_0. T diag alpha_k -> lane k, offdiag beta_{k+1}^2 -> lane k.
    float q = (t == 0) ? 1.0f : 0.0f;
    qbp[t] = q;
    MEMFENCE();
    float qp = 0.0f, bprev = 0.0f;
    float dval = 0.0f, e2val = 0.0f;
    #pragma unroll 1
    for (int k = 0; k < KSTEPS - 1; ++k) {
        // matvec: 4 independent 8-deep pk-FMA chains; operands direct from LDS
        f32x2 a0 = {0.0f, 0.0f}, a1 = {0.0f, 0.0f};
        f32x2 a2 = {0.0f, 0.0f}, a3 = {0.0f, 0.0f};
        #pragma unroll
        for (int m = 0; m < 32; m += 4) {
            a0 = __builtin_elementwise_fma(r2[m],     qb2[m],     a0);
            a1 = __builtin_elementwise_fma(r2[m + 1], qb2[m + 1], a1);
            a2 = __builtin_elementwise_fma(r2[m + 2], qb2[m + 2], a2);
            a3 = __builtin_elementwise_fma(r2[m + 3], qb2[m + 3], a3);
        }
        f32x2 st = (a0 + a1) + (a2 + a3);
        float w = st.x + st.y;
        w = fmaf(-bprev, qp, w);
        // merged independent reductions
        float alpha = wave_sum(q * w);
        float sww = wave_sum(w * w);
        float b2 = fmaxf(fmaf(-alpha, alpha, sww), 0.0f);
        float binv = (b2 > 1e-20f) ? rsqrtf(b2) : 0.0f;
        float wn = fmaf(-alpha, q, w);
        qp = q;
        q = wn * binv;
        qbp[t] = q;                       // publish next q ASAP
        MEMFENCE();
        // shadow work (under the write->read gap)
        bool cap = (t == k);
        dval = cap ? alpha : dval;
        e2val = cap ? b2 : e2val;         // beta_{k+1}^2
        bprev = b2 * binv;                // sqrt(b2)
    }
    // peeled last step (k = KSTEPS-1): only alpha needed
    {
        f32x2 a0 = {0.0f, 0.0f}, a1 = {0.0f, 0.0f};
        f32x2 a2 = {0.0f, 0.0f}, a3 = {0.0f, 0.0f};
        #pragma unroll
        for (int m = 0; m < 32; m += 4) {
            a0 = __builtin_elementwise_fma(r2[m],     qb2[m],     a0);
            a1 = __builtin_elementwise_fma(r2[m + 1], qb2[m + 1], a1);
            a2 = __builtin_elementwise_fma(r2[m + 2], qb2[m + 2], a2);
            a3 = __builtin_elementwise_fma(r2[m + 3], qb2[m + 3], a3);
        }
        f32x2 st = (a0 + a1) + (a2 + a3);
        float w = st.x + st.y;
        w = fmaf(-bprev, qp, w);
        float alpha = wave_sum(q * w);
        dval = (t == KSTEPS - 1) ? alpha : dval;
        // lane KSTEPS-1 e2val stays 0 -> truncated T decoupled
    }

    sturm_out<KSTEPS>(dval, e2val, idx_eff, t, b, out);
}

// ===== Householder path: interior indices (exact-count Sturm needs a
// ghost-free tridiagonal). Verified R12 structure. =====
template<int K0, int K1>
__device__ __forceinline__ void tri_chunk(f32x2 (&r2)[32], float& colreg,
                                          float& dval, float& e2val, const int t) {
    #pragma unroll 1
    for (int k = K0; k < K1; ++k) {
        float akt = (t > k) ? colreg : 0.0f;
        float s2 = wave_sum(akt * akt);
        float a1 = rl(akt, k + 1);
        float sigma = sqrtf(s2);
        float alpha = (a1 >= 0.0f) ? -sigma : sigma;
        e2val = (t == k) ? s2 : e2val;
        float vt = akt - ((t == k + 1) ? alpha : 0.0f);
        float vtv = 2.0f * (s2 - alpha * a1);
        float beta = (vtv > 1e-30f) ? 2.0f * __builtin_amdgcn_rcpf(vtv) : 0.0f;

        float pre_col = colreg;
        #pragma unroll
        for (int j = K0 + 1; j <= K1; ++j)
            if (j == k + 1) pre_col = (j & 1) ? r2[j >> 1].y : r2[j >> 1].x;

        f32x2 acc0 = {0.0f, 0.0f}, acc1 = {0.0f, 0.0f};
        #pragma unroll
        for (int p = K0 / 2; p < 32; ++p) {
            f32x2 a;
            a.x = rl(akt, 2 * p);
            a.y = rl(akt, 2 * p + 1);
            if (p & 1) acc1 = __builtin_elementwise_fma(r2[p], a, acc1);
            else       acc0 = __builtin_elementwise_fma(r2[p], a, acc0);
        }
        float ut = (acc0.x + acc0.y) + (acc1.x + acc1.y) - alpha * pre_col;
        float vtu = wave_sum(vt * ut);
        float c  = 0.5f * beta * beta * vtu;
        float p1 = vt * beta;
        float p2 = (t > k) ? (beta * ut - 2.0f * c * vt) : 0.0f;
        float uk1 = rl(ut, k + 1);
        float ncol = pre_col - p1 * uk1 - p2 * a1 + alpha * p2;

        f32x2 np1; np1.x = -p1; np1.y = -p1;
        f32x2 np2; np2.x = -p2; np2.y = -p2;
        #pragma unroll
        for (int p = K0 / 2; p < 32; ++p) {
            f32x2 u, a;
            u.x = rl(ut, 2 * p);
            u.y = rl(ut, 2 * p + 1);
            a.x = rl(akt, 2 * p);
            a.y = rl(akt, 2 * p + 1);
            r2[p] = __builtin_elementwise_fma(np1, u,
                    __builtin_elementwise_fma(np2, a, r2[p]));
        }
        #pragma unroll
        for (int j = K0 + 1; j <= K1; ++j) {
            if (j == k + 1) {
                if (j & 1) r2[j >> 1].y = ncol; else r2[j >> 1].x = ncol;
            }
        }
        colreg = ncol;
        dval = (t == k + 1) ? ncol : dval;
    }
}

__global__ __launch_bounds__(256, 1)
void householder_kernel(const float* __restrict__ x, const float* __restrict__ y,
                        const float* __restrict__ ws, const int* __restrict__ idxp,
                        float* __restrict__ out, int batch) {
    int idx = idxp[0];
    idx = idx < 0 ? 0 : (idx > NDIM - 1 ? NDIM - 1 : idx);
    if (idx == 0 || idx == NDIM - 1) return;   // handled by lanczos kernel

    const int t = threadIdx.x & 63;
    const int b = blockIdx.x * 4 + (threadIdx.x >> 6);
    if (b >= batch) return;

    const float xi = x[b * NDIM + t];
    const float yi = y[b * NDIM + t];
    f32x2 r2[32];
    build_rows(r2, ws, xi, yi, t);

    float colreg = r2[0].x;
    float dval = (t == 0) ? r2[0].x : 0.0f;
    float e2val = 0.0f;
    tri_chunk< 0,  8>(r2, colreg, dval, e2val, t);
    tri_chunk< 8, 16>(r2, colreg, dval, e2val, t);
    tri_chunk<16, 24>(r2, colreg, dval, e2val, t);
    tri_chunk<24, 32>(r2, colreg, dval, e2val, t);
    tri_chunk<32, 40>(r2, colreg, dval, e2val, t);
    tri_chunk<40, 48>(r2, colreg, dval, e2val, t);
    tri_chunk<48, 56>(r2, colreg, dval, e2val, t);
    tri_chunk<56, 62>(r2, colreg, dval, e2val, t);

    float e62 = rl(colreg, 63);
    e2val = (t == 62) ? e62 * e62 : e2val;
    dval = (t == 63) ? r2[31].y : dval;

    sturm_out<NDIM>(dval, e2val, idx, t, b, out);
}

extern "C" void kernel_launch(void* const* d_in, const int* in_sizes, int n_in,
                              void* d_out, int out_size, void* d_ws, size_t ws_size,
                              hipStream_t stream) {
    const float* x = (const float*)d_in[0];
    const float* y = (const float*)d_in[1];
    const float* A = (const float*)d_in[2];
    const float* B = (const float*)d_in[3];
    const float* C = (const float*)d_in[4];
    const int* idxp = (const int*)d_in[5];
    float* out = (float*)d_out;
    float* ws = (float*)d_ws;
    int batch = in_sizes[0] / NDIM;

    hipLaunchKernelGGL(prep_kernel, dim3(1), dim3(64), 0, stream, A, B, C, ws);
    hipLaunchKernelGGL(lanczos_kernel, dim3((batch + 3) / 4), dim3(256), 0, stream,
                       x, y, ws, idxp, out, batch);
    hipLaunchKernelGGL(householder_kernel, dim3((batch + 3) / 4), dim3(256), 0, stream,
                       x, y, ws, idxp, out, batch);
}

// Round 22
// 327.888 us; speedup vs baseline: 3.2397x; 3.2397x over previous
//
#include <hip/hip_runtime.h>
#include <math.h>

#define NDIM 64
#define KSTEPS 32
typedef float f32x2 __attribute__((ext_vector_type(2)));

#define MEMFENCE() asm volatile("" ::: "memory")

// Broadcast lane `lane`'s value to all lanes (uniform / SGPR).
__device__ __forceinline__ float rl(float v, int lane) {
    return __uint_as_float((unsigned)__builtin_amdgcn_readlane(__float_as_uint(v), lane));
}

// DPP add step with compile-time control/row mask.
template<int CTRL, int ROW_MASK>
__device__ __forceinline__ float dpp_add(float x) {
    int m = __builtin_amdgcn_update_dpp(0, __float_as_int(x), CTRL, ROW_MASK, 0xf, true);
    return x + __int_as_float(m);
}
// Full-wave64 sum via DPP; total lands in lane 63, broadcast via readlane.
__device__ __forceinline__ float wave_sum(float x) {
    x = dpp_add<0x111, 0xf>(x);   // row_shr:1
    x = dpp_add<0x112, 0xf>(x);   // row_shr:2
    x = dpp_add<0x114, 0xf>(x);   // row_shr:4
    x = dpp_add<0x118, 0xf>(x);   // row_shr:8
    x = dpp_add<0x142, 0xa>(x);   // row_bcast:15 -> rows 1,3
    x = dpp_add<0x143, 0xc>(x);   // row_bcast:31 -> row 3
    return rl(x, 63);
}
__device__ __forceinline__ float wave_min(float v) {
    #pragma unroll
    for (int off = 1; off < 64; off <<= 1) v = fminf(v, __shfl_xor(v, off, 64));
    return v;
}
__device__ __forceinline__ float wave_max(float v) {
    #pragma unroll
    for (int off = 1; off < 64; off <<= 1) v = fmaxf(v, __shfl_xor(v, off, 64));
    return v;
}

// Build symmetrized row t into r2 (32 x f32x2) using readlane broadcasts
// (used by the householder fallback path only).
__device__ __forceinline__ void build_rows(f32x2 (&r2)[32], const float* ws,
                                           float xi, float yi, int t) {
    const float4* Sa4 = (const float4*)(ws + t * NDIM);
    const float4* Bh4 = (const float4*)(ws + 4096 + t * NDIM);
    const float4* Bt4 = (const float4*)(ws + 8192 + t * NDIM);
    const float4* Ch4 = (const float4*)(ws + 12288 + t * NDIM);
    const float4* Ct4 = (const float4*)(ws + 16384 + t * NDIM);
    #pragma unroll
    for (int q = 0; q < 16; ++q) {
        float4 sa = Sa4[q], bh = Bh4[q], bt = Bt4[q], ch = Ch4[q], ct = Ct4[q];
        float x0 = rl(xi, 4 * q),     y0 = rl(yi, 4 * q);
        float x1 = rl(xi, 4 * q + 1), y1 = rl(yi, 4 * q + 1);
        float x2 = rl(xi, 4 * q + 2), y2 = rl(yi, 4 * q + 2);
        float x3 = rl(xi, 4 * q + 3), y3 = rl(yi, 4 * q + 3);
        float e0 = fmaf(bh.x, x0, fmaf(bt.x, xi, fmaf(ch.x, y0, fmaf(ct.x, yi, sa.x))));
        float e1 = fmaf(bh.y, x1, fmaf(bt.y, xi, fmaf(ch.y, y1, fmaf(ct.y, yi, sa.y))));
        float e2 = fmaf(bh.z, x2, fmaf(bt.z, xi, fmaf(ch.z, y2, fmaf(ct.z, yi, sa.z))));
        float e3 = fmaf(bh.w, x3, fmaf(bt.w, xi, fmaf(ch.w, y3, fmaf(ct.w, yi, sa.w))));
        r2[2 * q].x = e0;     r2[2 * q].y = e1;
        r2[2 * q + 1].x = e2; r2[2 * q + 1].y = e3;
    }
}

// Shared tail: Gershgorin bounds over lanes < NACT + 64-way Sturm multisection
// (register/readlane form; recurrence length NACT at compile time).
template<int NACT>
__device__ __forceinline__ void sturm_out(float dval, float e2val, int idx,
                                          int t, int b, float* out) {
    bool act = (t < NACT);
    float eabs = sqrtf(e2val);
    float eprev = __shfl_up(eabs, 1, 64);
    eprev = (t == 0) ? 0.0f : eprev;
    float rad = eabs + eprev;
    float lo = wave_min(act ? dval - rad : 1e30f);
    float hi = wave_max(act ? dval + rad : -1e30f);
    float pad = 1e-3f + 1e-5f * fmaxf(fabsf(lo), fabsf(hi));
    lo -= pad;
    hi += pad;

    #pragma unroll 1
    for (int it = 0; it < 2; ++it) {
        float wdt = (hi - lo) * (1.0f / 65.0f);
        float s = lo + wdt * (float)(t + 1);
        float q = rl(dval, 0) - s;
        q = (fabsf(q) < 1e-12f) ? -1e-12f : q;
        int cnt = (q < 0.0f) ? 1 : 0;
        #pragma unroll
        for (int i = 1; i < NACT; ++i) {
            q = rl(dval, i) - s - rl(e2val, i - 1) * __builtin_amdgcn_rcpf(q);
            q = (fabsf(q) < 1e-12f) ? -1e-12f : q;
            cnt += (q < 0.0f) ? 1 : 0;
        }
        unsigned long long m = __ballot(cnt <= idx);
        int p = (int)__popcll(m);
        float nlo = lo + wdt * (float)p;
        float nhi = lo + wdt * (float)(p + 1);
        lo = nlo;
        hi = (p >= 64) ? hi : nhi;
    }
    if (t == 0) out[b] = 0.5f * (lo + hi);
}

// One-time prep: Sa = 0.5(A+A^T), Bh = 0.5B, Bt = 0.5B^T, Ch = 0.5C, Ct = 0.5C^T.
__global__ __launch_bounds__(64)
void prep_kernel(const float* __restrict__ A, const float* __restrict__ B,
                 const float* __restrict__ C, float* __restrict__ ws) {
    const int t = threadIdx.x;
    float* Sa = ws;
    float* Bh = ws + 4096;
    float* Bt = ws + 8192;
    float* Ch = ws + 12288;
    float* Ct = ws + 16384;
    for (int j = 0; j < NDIM; ++j) {
        Sa[t * NDIM + j] = 0.5f * (A[t * NDIM + j] + A[j * NDIM + t]);
        Bh[t * NDIM + j] = 0.5f * B[t * NDIM + j];
        Bt[t * NDIM + j] = 0.5f * B[j * NDIM + t];
        Ch[t * NDIM + j] = 0.5f * C[t * NDIM + j];
        Ct[t * NDIM + j] = 0.5f * C[j * NDIM + t];
    }
}

// ===== Truncated Lanczos (K=32), extreme indices (idx==0 or idx==63).
// K=32 is the validated convergence point: absmax 0.125 (bf16-ulp floor) at
// K=32/48/64; K=24 fails (absmax 1.0). Build fully pk-FMA (x/y via LDS f32x2
// broadcast). launch_bounds(256,4): VGPR=64 (r2 resident), ~4 waves/SIMD.
__global__ __launch_bounds__(256, 4)
void lanczos_kernel(const float* __restrict__ x, const float* __restrict__ y,
                    const float* __restrict__ ws, const int* __restrict__ idxp,
                    float* __restrict__ out, int batch) {
    int idx = idxp[0];
    idx = idx < 0 ? 0 : (idx > NDIM - 1 ? NDIM - 1 : idx);
    if (idx != 0 && idx != NDIM - 1) return;   // interior: householder kernel
    const int idx_eff = (idx == 0) ? 0 : (KSTEPS - 1);

    const int t = threadIdx.x & 63;
    const int wv = threadIdx.x >> 6;
    const int b = blockIdx.x * 4 + wv;
    if (b >= batch) return;

    __shared__ f32x2 qbs[4][64];
    __shared__ float ybs[4][64];
    f32x2* qb2 = qbs[wv];
    float* qbp = (float*)qb2;
    float* ybp = ybs[wv];

    const float xi = x[b * NDIM + t];
    const float yi = y[b * NDIM + t];
    qbp[t] = xi;                       // x broadcast (buffer reused for q later)
    ybp[t] = yi;                       // y broadcast
    MEMFENCE();

    const float4* Sa4 = (const float4*)(ws + t * NDIM);
    const float4* Bh4 = (const float4*)(ws + 4096 + t * NDIM);
    const float4* Bt4 = (const float4*)(ws + 8192 + t * NDIM);
    const float4* Ch4 = (const float4*)(ws + 12288 + t * NDIM);
    const float4* Ct4 = (const float4*)(ws + 16384 + t * NDIM);
    const f32x2* xb2 = (const f32x2*)qbp;
    const f32x2* yb2 = (const f32x2*)ybp;

    f32x2 xi2; xi2.x = xi; xi2.y = xi;
    f32x2 yi2; yi2.x = yi; yi2.y = yi;

    // r_sym[t] = Sa + Bh*x[j] + Bt*x[t] + Ch*y[j] + Ct*y[t], all pk-FMA.
    f32x2 r2[32];
    #pragma unroll
    for (int qd = 0; qd < 16; ++qd) {
        float4 sa = Sa4[qd], bh = Bh4[qd], bt = Bt4[qd], ch = Ch4[qd], ct = Ct4[qd];
        f32x2 sa01; sa01.x = sa.x; sa01.y = sa.y;
        f32x2 sa23; sa23.x = sa.z; sa23.y = sa.w;
        f32x2 bh01; bh01.x = bh.x; bh01.y = bh.y;
        f32x2 bh23; bh23.x = bh.z; bh23.y = bh.w;
        f32x2 bt01; bt01.x = bt.x; bt01.y = bt.y;
        f32x2 bt23; bt23.x = bt.z; bt23.y = bt.w;
        f32x2 ch01; ch01.x = ch.x; ch01.y = ch.y;
        f32x2 ch23; ch23.x = ch.z; ch23.y = ch.w;
        f32x2 ct01; ct01.x = ct.x; ct01.y = ct.y;
        f32x2 ct23; ct23.x = ct.z; ct23.y = ct.w;
        f32x2 x01 = xb2[2 * qd], x23 = xb2[2 * qd + 1];
        f32x2 y01 = yb2[2 * qd], y23 = yb2[2 * qd + 1];
        f32x2 r01 = __builtin_elementwise_fma(bh01, x01,
                    __builtin_elementwise_fma(bt01, xi2,
                    __builtin_elementwise_fma(ch01, y01,
                    __builtin_elementwise_fma(ct01, yi2, sa01))));
        f32x2 r23 = __builtin_elementwise_fma(bh23, x23,
                    __builtin_elementwise_fma(bt23, xi2,
                    __builtin_elementwise_fma(ch23, y23,
                    __builtin_elementwise_fma(ct23, yi2, sa23))));
        r2[2 * qd] = r01;
        r2[2 * qd + 1] = r23;
    }
    MEMFENCE();                        // all xb2 reads issued before q0 overwrite

    // Lanczos: q0 = e_0. T diag alpha_k -> lane k, offdiag beta_{k+1}^2 -> lane k.
    float q = (t == 0) ? 1.0f : 0.0f;
    qbp[t] = q;
    MEMFENCE();
    float qp = 0.0f, bprev = 0.0f;
    float dval = 0.0f, e2val = 0.0f;
    #pragma unroll 1
    for (int k = 0; k < KSTEPS - 1; ++k) {
        // matvec: 4 independent 8-deep pk-FMA chains; operands direct from LDS
        f32x2 a0 = {0.0f, 0.0f}, a1 = {0.0f, 0.0f};
        f32x2 a2 = {0.0f, 0.0f}, a3 = {0.0f, 0.0f};
        #pragma unroll
        for (int m = 0; m < 32; m += 4) {
            a0 = __builtin_elementwise_fma(r2[m],     qb2[m],     a0);
            a1 = __builtin_elementwise_fma(r2[m + 1], qb2[m + 1], a1);
            a2 = __builtin_elementwise_fma(r2[m + 2], qb2[m + 2], a2);
            a3 = __builtin_elementwise_fma(r2[m + 3], qb2[m + 3], a3);
        }
        f32x2 st = (a0 + a1) + (a2 + a3);
        float w = st.x + st.y;
        w = fmaf(-bprev, qp, w);
        // merged independent reductions
        float alpha = wave_sum(q * w);
        float sww = wave_sum(w * w);
        float b2 = fmaxf(fmaf(-alpha, alpha, sww), 0.0f);
        float binv = (b2 > 1e-20f) ? rsqrtf(b2) : 0.0f;
        float wn = fmaf(-alpha, q, w);
        qp = q;
        q = wn * binv;
        qbp[t] = q;                       // publish next q ASAP
        MEMFENCE();
        // shadow work (under the write->read gap)
        bool cap = (t == k);
        dval = cap ? alpha : dval;
        e2val = cap ? b2 : e2val;         // beta_{k+1}^2
        bprev = b2 * binv;                // sqrt(b2)
    }
    // peeled last step (k = KSTEPS-1): only alpha needed
    {
        f32x2 a0 = {0.0f, 0.0f}, a1 = {0.0f, 0.0f};
        f32x2 a2 = {0.0f, 0.0f}, a3 = {0.0f, 0.0f};
        #pragma unroll
        for (int m = 0; m < 32; m += 4) {
            a0 = __builtin_elementwise_fma(r2[m],     qb2[m],     a0);
            a1 = __builtin_elementwise_fma(r2[m + 1], qb2[m + 1], a1);
            a2 = __builtin_elementwise_fma(r2[m + 2], qb2[m + 2], a2);
            a3 = __builtin_elementwise_fma(r2[m + 3], qb2[m + 3], a3);
        }
        f32x2 st = (a0 + a1) + (a2 + a3);
        float w = st.x + st.y;
        w = fmaf(-bprev, qp, w);
        float alpha = wave_sum(q * w);
        dval = (t == KSTEPS - 1) ? alpha : dval;
        // lane KSTEPS-1 e2val stays 0 -> truncated T decoupled
    }

    sturm_out<KSTEPS>(dval, e2val, idx_eff, t, b, out);
}

// ===== Householder path: interior indices (exact-count Sturm needs a
// ghost-free tridiagonal). Verified R12 structure. =====
template<int K0, int K1>
__device__ __forceinline__ void tri_chunk(f32x2 (&r2)[32], float& colreg,
                                          float& dval, float& e2val, const int t) {
    #pragma unroll 1
    for (int k = K0; k < K1; ++k) {
        float akt = (t > k) ? colreg : 0.0f;
        float s2 = wave_sum(akt * akt);
        float a1 = rl(akt, k + 1);
        float sigma = sqrtf(s2);
        float alpha = (a1 >= 0.0f) ? -sigma : sigma;
        e2val = (t == k) ? s2 : e2val;
        float vt = akt - ((t == k + 1) ? alpha : 0.0f);
        float vtv = 2.0f * (s2 - alpha * a1);
        float beta = (vtv > 1e-30f) ? 2.0f * __builtin_amdgcn_rcpf(vtv) : 0.0f;

        float pre_col = colreg;
        #pragma unroll
        for (int j = K0 + 1; j <= K1; ++j)
            if (j == k + 1) pre_col = (j & 1) ? r2[j >> 1].y : r2[j >> 1].x;

        f32x2 acc0 = {0.0f, 0.0f}, acc1 = {0.0f, 0.0f};
        #pragma unroll
        for (int p = K0 / 2; p < 32; ++p) {
            f32x2 a;
            a.x = rl(akt, 2 * p);
            a.y = rl(akt, 2 * p + 1);
            if (p & 1) acc1 = __builtin_elementwise_fma(r2[p], a, acc1);
            else       acc0 = __builtin_elementwise_fma(r2[p], a, acc0);
        }
        float ut = (acc0.x + acc0.y) + (acc1.x + acc1.y) - alpha * pre_col;
        float vtu = wave_sum(vt * ut);
        float c  = 0.5f * beta * beta * vtu;
        float p1 = vt * beta;
        float p2 = (t > k) ? (beta * ut - 2.0f * c * vt) : 0.0f;
        float uk1 = rl(ut, k + 1);
        float ncol = pre_col - p1 * uk1 - p2 * a1 + alpha * p2;

        f32x2 np1; np1.x = -p1; np1.y = -p1;
        f32x2 np2; np2.x = -p2; np2.y = -p2;
        #pragma unroll
        for (int p = K0 / 2; p < 32; ++p) {
            f32x2 u, a;
            u.x = rl(ut, 2 * p);
            u.y = rl(ut, 2 * p + 1);
            a.x = rl(akt, 2 * p);
            a.y = rl(akt, 2 * p + 1);
            r2[p] = __builtin_elementwise_fma(np1, u,
                    __builtin_elementwise_fma(np2, a, r2[p]));
        }
        #pragma unroll
        for (int j = K0 + 1; j <= K1; ++j) {
            if (j == k + 1) {
                if (j & 1) r2[j >> 1].y = ncol; else r2[j >> 1].x = ncol;
            }
        }
        colreg = ncol;
        dval = (t == k + 1) ? ncol : dval;
    }
}

__global__ __launch_bounds__(256, 1)
void householder_kernel(const float* __restrict__ x, const float* __restrict__ y,
                        const float* __restrict__ ws, const int* __restrict__ idxp,
                        float* __restrict__ out, int batch) {
    int idx = idxp[0];
    idx = idx < 0 ? 0 : (idx > NDIM - 1 ? NDIM - 1 : idx);
    if (idx == 0 || idx == NDIM - 1) return;   // handled by lanczos kernel

    const int t = threadIdx.x & 63;
    const int b = blockIdx.x * 4 + (threadIdx.x >> 6);
    if (b >= batch) return;

    const float xi = x[b * NDIM + t];
    const float yi = y[b * NDIM + t];
    f32x2 r2[32];
    build_rows(r2, ws, xi, yi, t);

    float colreg = r2[0].x;
    float dval = (t == 0) ? r2[0].x : 0.0f;
    float e2val = 0.0f;
    tri_chunk< 0,  8>(r2, colreg, dval, e2val, t);
    tri_chunk< 8, 16>(r2, colreg, dval, e2val, t);
    tri_chunk<16, 24>(r2, colreg, dval, e2val, t);
    tri_chunk<24, 32>(r2, colreg, dval, e2val, t);
    tri_chunk<32, 40>(r2, colreg, dval, e2val, t);
    tri_chunk<40, 48>(r2, colreg, dval, e2val, t);
    tri_chunk<48, 56>(r2, colreg, dval, e2val, t);
    tri_chunk<56, 62>(r2, colreg, dval, e2val, t);

    float e62 = rl(colreg, 63);
    e2val = (t == 62) ? e62 * e62 : e2val;
    dval = (t == 63) ? r2[31].y : dval;

    sturm_out<NDIM>(dval, e2val, idx, t, b, out);
}

extern "C" void kernel_launch(void* const* d_in, const int* in_sizes, int n_in,
                              void* d_out, int out_size, void* d_ws, size_t ws_size,
                              hipStream_t stream) {
    const float* x = (const float*)d_in[0];
    const float* y = (const float*)d_in[1];
    const float* A = (const float*)d_in[2];
    const float* B = (const float*)d_in[3];
    const float* C = (const float*)d_in[4];
    const int* idxp = (const int*)d_in[5];
    float* out = (float*)d_out;
    float* ws = (float*)d_ws;
    int batch = in_sizes[0] / NDIM;

    hipLaunchKernelGGL(prep_kernel, dim3(1), dim3(64), 0, stream, A, B, C, ws);
    hipLaunchKernelGGL(lanczos_kernel, dim3((batch + 3) / 4), dim3(256), 0, stream,
                       x, y, ws, idxp, out, batch);
    hipLaunchKernelGGL(householder_kernel, dim3((batch + 3) / 4), dim3(256), 0, stream,
                       x, y, ws, idxp, out, batch);
}